// Round 1
// baseline (355.658 us; speedup 1.0000x reference)
//
#include <hip/hip_runtime.h>

#define ALPHA 0.1f
#define NUM_CLASSES 10

typedef __attribute__((ext_vector_type(8))) short bf16x8;
typedef __attribute__((ext_vector_type(4))) float f32x4;

// ---------------------------------------------------------------------------
// ws layout (bytes):
//   loss  @ 0   : float[1]
//   counts@ 4   : uint[100]
// (zeroed each launch via hipMemsetAsync)
//
// ROUND 11: barrier-free restructure.
//   Old: centers in regs (32/wave), x staged through LDS, 2 barriers/tile,
//        cross-wave combine of swe/swd/best through LDS.  Counters showed
//        nothing saturated (VALU 48%, MFMA 14%) -> structure-bound.
//   New: centers live in LDS as pre-built -2c split bf16 A-frags (64 KB,
//        built once per block); each wave keeps its OWN 16 points in regs
//        as B-frags and sweeps all 16 center groups.  Per-point reductions
//        are wave-local -> zero main-loop barriers, zero cross-wave combine.
//   u = 1 + d is BITWISE identical to round 10 (same pack/split/MFMA chain,
//        same acc preload x2 + (c2+1), same argmin bit-pack) -> counts/acc
//        unchanged; only swe/swd summation order differs (fp32 reorder).
//   counts: LDS atomics + one flush per block (was global atomic per point).
// ---------------------------------------------------------------------------

__device__ __forceinline__ unsigned pack2(float a, float b) {
    // bf16(a) lo16 | bf16(b) hi16 (truncation -> exact Dekker hi split)
    return (__float_as_uint(b) & 0xFFFF0000u) | (__float_as_uint(a) >> 16);
}
__device__ __forceinline__ float truncbf(float a) {
    return __uint_as_float(__float_as_uint(a) & 0xFFFF0000u);
}

// 512 threads = 8 waves.  Wave w owns points [t*128 + w*16, +16).
// Lane l: point row pr = l&15, k-group kg = l>>4 (8 k's per group).
// A-frags in LDS: [g][f][lane][16B], g = center group (16 centers),
// f: 0 = -2c hi k0-31, 1 = hi k32-63, 2 = lo k0-31, 3 = lo k32-63.
__global__ __launch_bounds__(512, 4) void dist_kernel(
    const float* __restrict__ x,
    const int*   __restrict__ y,
    const float* __restrict__ centers,
    float* __restrict__ loss_acc,
    unsigned int* __restrict__ counts,
    int NT)
{
    __shared__ __align__(16) char afr[16 * 4 * 64 * 16];   // 64 KB A-frags
    __shared__ float c2s1[256];                            // c2 + 1
    __shared__ unsigned int counts_l[100];

    const int tid = threadIdx.x;
    const int w   = tid >> 6;
    const int l   = tid & 63;
    const int pr  = l & 15;
    const int kg  = l >> 4;

    if (tid < 100) counts_l[tid] = 0u;

    // ---- startup: center norms + 1 (one center per thread) ----
    if (tid < 256) {
        const float4* crow = (const float4*)(centers + tid * 64);
        float s = 0.f;
#pragma unroll
        for (int j = 0; j < 16; ++j) {
            float4 v = crow[j];
            s = fmaf(v.x, v.x, s); s = fmaf(v.y, v.y, s);
            s = fmaf(v.z, v.z, s); s = fmaf(v.w, v.w, s);
        }
        c2s1[tid] = s + 1.f;
    }

    // ---- startup: build ALL center A-frags (pre-scaled by -2) into LDS ----
    // 256 centers x 8 chunks-of-8-floats = 2048 jobs over 512 threads.
#pragma unroll
    for (int it = 0; it < 4; ++it) {
        const int idx = (it << 9) | tid;        // 0..2047
        const int ct  = idx >> 3;               // center 0..255
        const int c8  = idx & 7;                // chunk: k = c8*8..c8*8+7
        const int g   = ct >> 4;
        const int kgg = c8 & 3;
        const int fhi = c8 >> 2;                // 0: k<32, 1: k>=32
        const int lc  = (ct & 15) | (kgg << 4); // consuming lane
        const float4* C = (const float4*)(centers + (size_t)ct * 64);
        const float4 v0 = C[c8 * 2];
        const float4 v1 = C[c8 * 2 + 1];
        const float m0x = -2.f * v0.x, m0y = -2.f * v0.y;
        const float m0z = -2.f * v0.z, m0w = -2.f * v0.w;
        const float m1x = -2.f * v1.x, m1y = -2.f * v1.y;
        const float m1z = -2.f * v1.z, m1w = -2.f * v1.w;
        uint4 hi, lo;
        hi.x = pack2(m0x, m0y); hi.y = pack2(m0z, m0w);
        hi.z = pack2(m1x, m1y); hi.w = pack2(m1z, m1w);
        lo.x = pack2(m0x - truncbf(m0x), m0y - truncbf(m0y));
        lo.y = pack2(m0z - truncbf(m0z), m0w - truncbf(m0w));
        lo.z = pack2(m1x - truncbf(m1x), m1y - truncbf(m1y));
        lo.w = pack2(m1z - truncbf(m1z), m1w - truncbf(m1w));
        *(uint4*)(afr + ((((g << 2) + fhi)     * 64 + lc) << 4)) = hi;
        *(uint4*)(afr + ((((g << 2) + fhi + 2) * 64 + lc) << 4)) = lo;
    }

    __syncthreads();   // the ONLY main-path barrier: A-frags/c2 ready

    // ---- prefetch first tile's x chunk + y label ----
    const int stride = gridDim.x;
    int t = blockIdx.x;
    float4 pv0, pv1, pv2, pv3;
    int ylab;
    {
        const size_t row = (size_t)(t * 128 + w * 16 + pr);
        const float4* X = (const float4*)(x + row * 64);
        pv0 = X[kg * 2]; pv1 = X[kg * 2 + 1];
        pv2 = X[8 + kg * 2]; pv3 = X[9 + kg * 2];
        ylab = y[t * 128 + w * 16 + pr];
    }

    float loss_local = 0.f;

    for (; t < NT; t += stride) {
        const float4 v0 = pv0, v1 = pv1, v2 = pv2, v3 = pv3;
        const int yl = ylab;

        // issue next tile's loads (latency hidden under the 16-group sweep)
        const int tn = t + stride;
        if (tn < NT) {
            const size_t row = (size_t)(tn * 128 + w * 16 + pr);
            const float4* X = (const float4*)(x + row * 64);
            pv0 = X[kg * 2]; pv1 = X[kg * 2 + 1];
            pv2 = X[8 + kg * 2]; pv3 = X[9 + kg * 2];
            ylab = y[tn * 128 + w * 16 + pr];
        }

        // x2 (identical op order to round 10 -> identical bits)
        float p = v0.x * v0.x;
        p = fmaf(v0.y, v0.y, p); p = fmaf(v0.z, v0.z, p); p = fmaf(v0.w, v0.w, p);
        p = fmaf(v1.x, v1.x, p); p = fmaf(v1.y, v1.y, p); p = fmaf(v1.z, v1.z, p); p = fmaf(v1.w, v1.w, p);
        p = fmaf(v2.x, v2.x, p); p = fmaf(v2.y, v2.y, p); p = fmaf(v2.z, v2.z, p); p = fmaf(v2.w, v2.w, p);
        p = fmaf(v3.x, v3.x, p); p = fmaf(v3.y, v3.y, p); p = fmaf(v3.z, v3.z, p); p = fmaf(v3.w, v3.w, p);
        p += __shfl_xor(p, 16);
        p += __shfl_xor(p, 32);

        // convert own x to split bf16 B-frags (never touches LDS)
        union { bf16x8 v; unsigned u[4]; } b0, b1, b2, b3;
        b0.u[0] = pack2(v0.x, v0.y); b0.u[1] = pack2(v0.z, v0.w);
        b0.u[2] = pack2(v1.x, v1.y); b0.u[3] = pack2(v1.z, v1.w);
        b1.u[0] = pack2(v2.x, v2.y); b1.u[1] = pack2(v2.z, v2.w);
        b1.u[2] = pack2(v3.x, v3.y); b1.u[3] = pack2(v3.z, v3.w);
        b2.u[0] = pack2(v0.x - truncbf(v0.x), v0.y - truncbf(v0.y));
        b2.u[1] = pack2(v0.z - truncbf(v0.z), v0.w - truncbf(v0.w));
        b2.u[2] = pack2(v1.x - truncbf(v1.x), v1.y - truncbf(v1.y));
        b2.u[3] = pack2(v1.z - truncbf(v1.z), v1.w - truncbf(v1.w));
        b3.u[0] = pack2(v2.x - truncbf(v2.x), v2.y - truncbf(v2.y));
        b3.u[1] = pack2(v2.z - truncbf(v2.z), v2.w - truncbf(v2.w));
        b3.u[2] = pack2(v3.x - truncbf(v3.x), v3.y - truncbf(v3.y));
        b3.u[3] = pack2(v3.z - truncbf(v3.z), v3.w - truncbf(v3.w));

        float swe = 0.f, swd = 0.f;
        unsigned best = 0xFFFFFFFFu;

        // sweep all 16 center groups; everything stays wave-local
#pragma unroll
        for (int g = 0; g < 16; ++g) {
            const uint4* A = (const uint4*)(afr + (g << 12)) + l;
            union { uint4 u4; bf16x8 v; } a0, a1, a2, a3;
            a0.u4 = A[0];   a1.u4 = A[64];
            a2.u4 = A[128]; a3.u4 = A[192];
            const float4 cq = *(const float4*)(c2s1 + g * 16 + kg * 4);

            f32x4 acc;
            acc[0] = p + cq.x; acc[1] = p + cq.y;
            acc[2] = p + cq.z; acc[3] = p + cq.w;
            acc = __builtin_amdgcn_mfma_f32_16x16x32_bf16(a0.v, b0.v, acc, 0, 0, 0); // mh.xh
            acc = __builtin_amdgcn_mfma_f32_16x16x32_bf16(a1.v, b1.v, acc, 0, 0, 0);
            acc = __builtin_amdgcn_mfma_f32_16x16x32_bf16(a2.v, b0.v, acc, 0, 0, 0); // ml.xh
            acc = __builtin_amdgcn_mfma_f32_16x16x32_bf16(a3.v, b1.v, acc, 0, 0, 0);
            acc = __builtin_amdgcn_mfma_f32_16x16x32_bf16(a0.v, b2.v, acc, 0, 0, 0); // mh.xl
            acc = __builtin_amdgcn_mfma_f32_16x16x32_bf16(a1.v, b3.v, acc, 0, 0, 0);

#pragma unroll
            for (int reg = 0; reg < 4; ++reg) {
                const float u = acc[reg];                         // u = 1 + d
                const unsigned kid = (unsigned)((g << 4) | (kg << 2) | reg);
                best = min(best, (__float_as_uint(u) & 0xFFFFFF00u) | kid);
                float wg = exp2f(-ALPHA * __log2f(u));
                swe += wg;
                swd = fmaf(wg, u, swd);
            }
        }

        // reduce over the 4 k-group lanes sharing point pr
        swe += __shfl_xor(swe, 16); swe += __shfl_xor(swe, 32);
        swd += __shfl_xor(swd, 16); swd += __shfl_xor(swd, 32);
        best = min(best, (unsigned)__shfl_xor((int)best, 16));
        best = min(best, (unsigned)__shfl_xor((int)best, 32));

        if (kg == 0) {
            loss_local += swd / swe - 1.f;   // Sum w*d / Sum w
            const unsigned bk = best & 0xFFu;
            if (bk < NUM_CLASSES) {
                atomicAdd(&counts_l[bk * NUM_CLASSES + yl], 1u);
            }
        }
    }

    // per-wave loss reduce -> one global atomic per wave
    float v = loss_local;
#pragma unroll
    for (int o = 32; o > 0; o >>= 1) v += __shfl_down(v, o);
    if (l == 0) atomicAdd(loss_acc, v);

    __syncthreads();
    if (tid < 100) {
        const unsigned c = counts_l[tid];
        if (c) atomicAdd(&counts[tid], c);
    }
}

// ---------------------------------------------------------------------------
// Finalize: greedy cluster->label assignment, exactly mirroring the reference.
// ---------------------------------------------------------------------------

__global__ void finalize_kernel(
    const float* __restrict__ loss_acc,
    const unsigned int* __restrict__ counts,
    float* __restrict__ out,
    int N)
{
    if (threadIdx.x == 0 && blockIdx.x == 0) {
        float c[NUM_CLASSES][NUM_CLASSES];
        for (int i = 0; i < NUM_CLASSES; ++i)
            for (int j = 0; j < NUM_CLASSES; ++j)
                c[i][j] = (float)counts[i * NUM_CLASSES + j];

        bool used[NUM_CLASSES];
        for (int i = 0; i < NUM_CLASSES; ++i) used[i] = false;

        float correct = 0.f;
        for (int i = 0; i < NUM_CLASSES; ++i) {
            float rowsum = 0.f;
            for (int j = 0; j < NUM_CLASSES; ++j) rowsum += c[i][j];
            bool has_points = rowsum > 0.f;

            int label = 0;
            float mx = c[i][0];
            for (int j = 1; j < NUM_CLASSES; ++j)
                if (c[i][j] > mx) { mx = c[i][j]; label = j; }

            if (used[label]) {
                float mm = used[0] ? 0.f : c[i][0];
                int l2 = 0;
                for (int j = 1; j < NUM_CLASSES; ++j) {
                    float v = used[j] ? 0.f : c[i][j];
                    if (v > mm) { mm = v; l2 = j; }
                }
                label = l2;
            }

            if (has_points) {
                correct += c[i][label];
                used[label] = true;
            }
        }
        out[0] = loss_acc[0];
        out[1] = correct / (float)N;
    }
}

// ---------------------------------------------------------------------------

extern "C" void kernel_launch(void* const* d_in, const int* in_sizes, int n_in,
                              void* d_out, int out_size, void* d_ws, size_t ws_size,
                              hipStream_t stream)
{
    const float* x       = (const float*)d_in[0];
    const int*   y       = (const int*)d_in[1];
    const float* centers = (const float*)d_in[2];
    float* out = (float*)d_out;

    const int N  = in_sizes[0] / 64;  // D = 64
    const int NT = N / 128;           // 128-point tiles

    float* loss          = (float*)d_ws;                       // 4 B
    unsigned int* counts = (unsigned int*)((char*)d_ws + 4);   // 400 B

    hipMemsetAsync(d_ws, 0, 512, stream);

    int grid = 512;                   // 2 blocks/CU (LDS 67 KB -> 2 resident)
    if (grid > NT) grid = NT;
    dist_kernel<<<grid, 512, 0, stream>>>(x, y, centers, loss, counts, NT);

    finalize_kernel<<<1, 64, 0, stream>>>(loss, counts, out, N);
}

// Round 2
// 160.405 us; speedup vs baseline: 2.2172x; 2.2172x over previous
//
#include <hip/hip_runtime.h>

#define ALPHA 0.1f
#define NUM_CLASSES 10

typedef __attribute__((ext_vector_type(8))) short bf16x8;
typedef __attribute__((ext_vector_type(4))) float f32x4;

// ---------------------------------------------------------------------------
// ws layout (bytes):
//   loss  @ 0   : float[1]
//   counts@ 4   : uint[100]
// (zeroed each launch via hipMemsetAsync)
//
// ROUND 12: R10 skeleton (proven 68us, no spills) with structural overheads
// removed.  R11's LDS-centers restructure spilled (267MB scratch writes) --
// reverted.  Changes vs R10, keeping the persistent register set identical
// (af 32 + pv 16 + c2r1 8) and the MFMA math bit-identical:
//  A. 128-point tiles, ALL 8 waves stage their own 16-pt subtile from
//     prefetched regs (R10: waves 4-7 idle at barA; 2 barriers/64pts ->
//     now 2 barriers/128pts).
//  B. Cross-group combine via LDS atomics (ds_add_f32 swe/swd, ds_min_u32
//     best) accumulated during the pt-phases; the combine phase is just
//     3 LDS reads + 1 div per point on waves 0-1 (R10: 12KB partial
//     arrays + 8-way serial tree on wave 0 while 7 waves wait).
//  C. counts through LDS atomics, one 100-word global flush per block
//     (R10: one global atomic per point on 100 hot addresses).
// ---------------------------------------------------------------------------

__device__ __forceinline__ unsigned pack2(float a, float b) {
    // bf16(a) lo16 | bf16(b) hi16 (truncation -> exact Dekker hi split)
    return (__float_as_uint(b) & 0xFFFF0000u) | (__float_as_uint(a) >> 16);
}
__device__ __forceinline__ float truncbf(float a) {
    return __uint_as_float(__float_as_uint(a) & 0xFFFF0000u);
}

// 512 threads = 8 waves. Wave w owns centers [w*32, w*32+32) (M dim) and
// stages points [t*128 + w*16, +16) (N dim).  Lane: pr = l&15 (point row),
// kg = l>>4 (k-group of 8 floats).
__global__ __launch_bounds__(512, 4) void dist_kernel(
    const float* __restrict__ x,
    const int*   __restrict__ y,
    const float* __restrict__ centers,
    float* __restrict__ loss_acc,
    unsigned int* __restrict__ counts,
    int NT)
{
    // bstage[pt][f][lane] : 16 B per lane, contiguous-lane layout (b128)
    __shared__ __align__(16) char bstage[8 * 4 * 64 * 16];   // 32 KB
    __shared__ float x2s[128];
    __shared__ float c2s[256];
    __shared__ float    comb_swe[128];
    __shared__ float    comb_swd[128];
    __shared__ unsigned comb_best[128];
    __shared__ unsigned counts_l[100];

    const int tid  = threadIdx.x;
    const int w    = tid >> 6;     // wave id = center group (32 centers)
    const int lane = tid & 63;
    const int q    = lane >> 4;    // k-group
    const int r    = lane & 15;    // point row within subtile

    if (tid < 100) counts_l[tid] = 0u;
    if (tid < 128) {
        comb_swe[tid] = 0.f; comb_swd[tid] = 0.f; comb_best[tid] = 0xFFFFFFFFu;
    }

    // ---- startup: center norms (one center per thread) ----
    if (tid < 256) {
        const float4* crow = (const float4*)(centers + tid * 64);
        float s = 0.f;
#pragma unroll
        for (int j = 0; j < 16; ++j) {
            float4 v = crow[j];
            s = fmaf(v.x, v.x, s); s = fmaf(v.y, v.y, s);
            s = fmaf(v.z, v.z, s); s = fmaf(v.w, v.w, s);
        }
        c2s[tid] = s;
    }

    // ---- startup: this wave's center A-frags, PRE-SCALED by -2 ----
    // af[ct][f]; f: 0=mh k0-31, 1=mh k32-63, 2=ml k0-31, 3=ml k32-63
    bf16x8 af[2][4];
#pragma unroll
    for (int ct = 0; ct < 2; ++ct) {
        const int row = w * 32 + ct * 16 + r;
        const float4* C = (const float4*)(centers + (size_t)row * 64);
        float4 v0 = C[q * 2], v1 = C[q * 2 + 1];       // k = q*8 .. q*8+7
        float4 v2 = C[8 + q * 2], v3 = C[9 + q * 2];   // k = 32+q*8 ..
        float4 m0 = make_float4(-2.f * v0.x, -2.f * v0.y, -2.f * v0.z, -2.f * v0.w);
        float4 m1 = make_float4(-2.f * v1.x, -2.f * v1.y, -2.f * v1.z, -2.f * v1.w);
        float4 m2 = make_float4(-2.f * v2.x, -2.f * v2.y, -2.f * v2.z, -2.f * v2.w);
        float4 m3 = make_float4(-2.f * v3.x, -2.f * v3.y, -2.f * v3.z, -2.f * v3.w);
        union { bf16x8 v; unsigned u[4]; } h0, h1, l0, l1;
        h0.u[0] = pack2(m0.x, m0.y); h0.u[1] = pack2(m0.z, m0.w);
        h0.u[2] = pack2(m1.x, m1.y); h0.u[3] = pack2(m1.z, m1.w);
        h1.u[0] = pack2(m2.x, m2.y); h1.u[1] = pack2(m2.z, m2.w);
        h1.u[2] = pack2(m3.x, m3.y); h1.u[3] = pack2(m3.z, m3.w);
        l0.u[0] = pack2(m0.x - truncbf(m0.x), m0.y - truncbf(m0.y));
        l0.u[1] = pack2(m0.z - truncbf(m0.z), m0.w - truncbf(m0.w));
        l0.u[2] = pack2(m1.x - truncbf(m1.x), m1.y - truncbf(m1.y));
        l0.u[3] = pack2(m1.z - truncbf(m1.z), m1.w - truncbf(m1.w));
        l1.u[0] = pack2(m2.x - truncbf(m2.x), m2.y - truncbf(m2.y));
        l1.u[1] = pack2(m2.z - truncbf(m2.z), m2.w - truncbf(m2.w));
        l1.u[2] = pack2(m3.x - truncbf(m3.x), m3.y - truncbf(m3.y));
        l1.u[3] = pack2(m3.z - truncbf(m3.z), m3.w - truncbf(m3.w));
        af[ct][0] = h0.v; af[ct][1] = h1.v; af[ct][2] = l0.v; af[ct][3] = l1.v;
    }

    // ---- prefetch first tile's x (every wave stages its own subtile) ----
    float4 pv0, pv1, pv2, pv3;
    {
        const int row = blockIdx.x * 128 + w * 16 + r;
        const float4* X = (const float4*)(x + (size_t)row * 64);
        pv0 = X[q * 2]; pv1 = X[q * 2 + 1];
        pv2 = X[8 + q * 2]; pv3 = X[9 + q * 2];
    }

    __syncthreads();   // startup: c2s / comb init visible

    // this lane's 8 center norms + 1: u = (x2 + c2 + 1) + (-2 x.c)
    float c2r1[2][4];
#pragma unroll
    for (int ct = 0; ct < 2; ++ct) {
        float4 v = *(const float4*)(c2s + w * 32 + ct * 16 + q * 4);
        c2r1[ct][0] = v.x + 1.f; c2r1[ct][1] = v.y + 1.f;
        c2r1[ct][2] = v.z + 1.f; c2r1[ct][3] = v.w + 1.f;
    }

    float loss_local = 0.f;

    for (int t = blockIdx.x; t < NT; t += gridDim.x) {
        // ---- y prefetch for this tile's combine (latency spans the tile) ----
        int ylab = 0;
        if (tid < 128) ylab = y[t * 128 + tid];

        // ---- stage: every wave converts its subtile from prefetched regs ----
        {
            float4 v0 = pv0, v1 = pv1, v2 = pv2, v3 = pv3;

            // issue next tile's loads immediately (latency hidden by MFMA phase)
            const int tn = t + gridDim.x;
            if (tn < NT) {
                const int row = tn * 128 + w * 16 + r;
                const float4* X = (const float4*)(x + (size_t)row * 64);
                pv0 = X[q * 2]; pv1 = X[q * 2 + 1];
                pv2 = X[8 + q * 2]; pv3 = X[9 + q * 2];
            }

            float p = v0.x * v0.x;
            p = fmaf(v0.y, v0.y, p); p = fmaf(v0.z, v0.z, p); p = fmaf(v0.w, v0.w, p);
            p = fmaf(v1.x, v1.x, p); p = fmaf(v1.y, v1.y, p); p = fmaf(v1.z, v1.z, p); p = fmaf(v1.w, v1.w, p);
            p = fmaf(v2.x, v2.x, p); p = fmaf(v2.y, v2.y, p); p = fmaf(v2.z, v2.z, p); p = fmaf(v2.w, v2.w, p);
            p = fmaf(v3.x, v3.x, p); p = fmaf(v3.y, v3.y, p); p = fmaf(v3.z, v3.z, p); p = fmaf(v3.w, v3.w, p);
            p += __shfl_xor(p, 16);
            p += __shfl_xor(p, 32);
            if (q == 0) x2s[w * 16 + r] = p;

            union { bf16x8 v; uint4 u4; unsigned u[4]; } h0, h1, l0, l1;
            h0.u[0] = pack2(v0.x, v0.y); h0.u[1] = pack2(v0.z, v0.w);
            h0.u[2] = pack2(v1.x, v1.y); h0.u[3] = pack2(v1.z, v1.w);
            h1.u[0] = pack2(v2.x, v2.y); h1.u[1] = pack2(v2.z, v2.w);
            h1.u[2] = pack2(v3.x, v3.y); h1.u[3] = pack2(v3.z, v3.w);
            l0.u[0] = pack2(v0.x - truncbf(v0.x), v0.y - truncbf(v0.y));
            l0.u[1] = pack2(v0.z - truncbf(v0.z), v0.w - truncbf(v0.w));
            l0.u[2] = pack2(v1.x - truncbf(v1.x), v1.y - truncbf(v1.y));
            l0.u[3] = pack2(v1.z - truncbf(v1.z), v1.w - truncbf(v1.w));
            l1.u[0] = pack2(v2.x - truncbf(v2.x), v2.y - truncbf(v2.y));
            l1.u[1] = pack2(v2.z - truncbf(v2.z), v2.w - truncbf(v2.w));
            l1.u[2] = pack2(v3.x - truncbf(v3.x), v3.y - truncbf(v3.y));
            l1.u[3] = pack2(v3.z - truncbf(v3.z), v3.w - truncbf(v3.w));
            *(uint4*)(bstage + (((w * 4 + 0) * 64 + lane) << 4)) = h0.u4;
            *(uint4*)(bstage + (((w * 4 + 1) * 64 + lane) << 4)) = h1.u4;
            *(uint4*)(bstage + (((w * 4 + 2) * 64 + lane) << 4)) = l0.u4;
            *(uint4*)(bstage + (((w * 4 + 3) * 64 + lane) << 4)) = l1.u4;
        }
        __syncthreads();   // barA: frags + x2s visible; prev combine done

        // ---- per 16-point subtile: MFMA (acc preloaded) then epilogue ----
#pragma unroll
        for (int pt = 0; pt < 8; ++pt) {
            union { uint4 u4; bf16x8 v; } b0, b1, b2, b3;
            b0.u4 = *(const uint4*)(bstage + (((pt * 4 + 0) * 64 + lane) << 4));
            b1.u4 = *(const uint4*)(bstage + (((pt * 4 + 1) * 64 + lane) << 4));
            b2.u4 = *(const uint4*)(bstage + (((pt * 4 + 2) * 64 + lane) << 4));
            b3.u4 = *(const uint4*)(bstage + (((pt * 4 + 3) * 64 + lane) << 4));
            const float x2p = x2s[pt * 16 + r];

            f32x4 acc[2];
#pragma unroll
            for (int ct = 0; ct < 2; ++ct) {
                f32x4 a;
                a[0] = x2p + c2r1[ct][0]; a[1] = x2p + c2r1[ct][1];
                a[2] = x2p + c2r1[ct][2]; a[3] = x2p + c2r1[ct][3];
                a = __builtin_amdgcn_mfma_f32_16x16x32_bf16(af[ct][0], b0.v, a, 0, 0, 0); // mh.xh
                a = __builtin_amdgcn_mfma_f32_16x16x32_bf16(af[ct][1], b1.v, a, 0, 0, 0);
                a = __builtin_amdgcn_mfma_f32_16x16x32_bf16(af[ct][2], b0.v, a, 0, 0, 0); // ml.xh
                a = __builtin_amdgcn_mfma_f32_16x16x32_bf16(af[ct][3], b1.v, a, 0, 0, 0);
                a = __builtin_amdgcn_mfma_f32_16x16x32_bf16(af[ct][0], b2.v, a, 0, 0, 0); // mh.xl
                a = __builtin_amdgcn_mfma_f32_16x16x32_bf16(af[ct][1], b3.v, a, 0, 0, 0);
                acc[ct] = a;
            }

            float swe = 0.f, swdu = 0.f;
            unsigned best = 0xFFFFFFFFu;
#pragma unroll
            for (int ct = 0; ct < 2; ++ct) {
#pragma unroll
                for (int reg = 0; reg < 4; ++reg) {
                    const float u = acc[ct][reg];          // u = 1 + d
                    const unsigned kid = (unsigned)(w * 32 + ct * 16 + q * 4 + reg);
                    best = min(best, (__float_as_uint(u) & 0xFFFFFF00u) | kid);
                    float wg = exp2f(-ALPHA * __log2f(u));
                    swe += wg;
                    swdu = fmaf(wg, u, swdu);
                }
            }
            // reduce over q (4 lanes share point pt*16+r)
            swe += __shfl_xor(swe, 16); swe += __shfl_xor(swe, 32);
            swdu += __shfl_xor(swdu, 16); swdu += __shfl_xor(swdu, 32);
            best = min(best, (unsigned)__shfl_xor((int)best, 16));
            best = min(best, (unsigned)__shfl_xor((int)best, 32));
            if (q == 0) {
                atomicAdd(&comb_swe[pt * 16 + r], swe);
                atomicAdd(&comb_swd[pt * 16 + r], swdu);
                atomicMin(&comb_best[pt * 16 + r], best);
            }
        }
        __syncthreads();   // barB: all groups' contributions accumulated

        // ---- combine: trivial per-point finish on waves 0-1 ----
        if (tid < 128) {
            const float SWE = comb_swe[tid];
            const float SWD = comb_swd[tid];
            const unsigned BEST = comb_best[tid];
            loss_local += SWD / SWE - 1.f;   // Sum w*d / Sum w  ==  swdu/swe - 1
            const unsigned bk = BEST & 0xFFu;
            if (bk < NUM_CLASSES) {
                atomicAdd(&counts_l[bk * NUM_CLASSES + ylab], 1u);
            }
            // re-arm accumulators for the next tile (raced only after next barA)
            comb_swe[tid] = 0.f; comb_swd[tid] = 0.f; comb_best[tid] = 0xFFFFFFFFu;
        }
        // next iteration's barA protects bstage / x2s / comb_* reuse
    }

    // per-wave loss reduce -> one global atomic per contributing wave
    if (w < 2) {
        float v = loss_local;
#pragma unroll
        for (int o = 32; o > 0; o >>= 1) v += __shfl_down(v, o);
        if (lane == 0) atomicAdd(loss_acc, v);
    }

    __syncthreads();
    if (tid < 100) {
        const unsigned c = counts_l[tid];
        if (c) atomicAdd(&counts[tid], c);
    }
}

// ---------------------------------------------------------------------------
// Finalize: greedy cluster->label assignment, exactly mirroring the reference.
// ---------------------------------------------------------------------------

__global__ void finalize_kernel(
    const float* __restrict__ loss_acc,
    const unsigned int* __restrict__ counts,
    float* __restrict__ out,
    int N)
{
    if (threadIdx.x == 0 && blockIdx.x == 0) {
        float c[NUM_CLASSES][NUM_CLASSES];
        for (int i = 0; i < NUM_CLASSES; ++i)
            for (int j = 0; j < NUM_CLASSES; ++j)
                c[i][j] = (float)counts[i * NUM_CLASSES + j];

        bool used[NUM_CLASSES];
        for (int i = 0; i < NUM_CLASSES; ++i) used[i] = false;

        float correct = 0.f;
        for (int i = 0; i < NUM_CLASSES; ++i) {
            float rowsum = 0.f;
            for (int j = 0; j < NUM_CLASSES; ++j) rowsum += c[i][j];
            bool has_points = rowsum > 0.f;

            int label = 0;
            float mx = c[i][0];
            for (int j = 1; j < NUM_CLASSES; ++j)
                if (c[i][j] > mx) { mx = c[i][j]; label = j; }

            if (used[label]) {
                float mm = used[0] ? 0.f : c[i][0];
                int l2 = 0;
                for (int j = 1; j < NUM_CLASSES; ++j) {
                    float v = used[j] ? 0.f : c[i][j];
                    if (v > mm) { mm = v; l2 = j; }
                }
                label = l2;
            }

            if (has_points) {
                correct += c[i][label];
                used[label] = true;
            }
        }
        out[0] = loss_acc[0];
        out[1] = correct / (float)N;
    }
}

// ---------------------------------------------------------------------------

extern "C" void kernel_launch(void* const* d_in, const int* in_sizes, int n_in,
                              void* d_out, int out_size, void* d_ws, size_t ws_size,
                              hipStream_t stream)
{
    const float* x       = (const float*)d_in[0];
    const int*   y       = (const int*)d_in[1];
    const float* centers = (const float*)d_in[2];
    float* out = (float*)d_out;

    const int N  = in_sizes[0] / 64;  // D = 64
    const int NT = N / 128;           // 128-point tiles

    float* loss          = (float*)d_ws;                       // 4 B
    unsigned int* counts = (unsigned int*)((char*)d_ws + 4);   // 400 B

    hipMemsetAsync(d_ws, 0, 512, stream);

    int grid = 1024;                  // 4 blocks/CU (LDS ~36 KB, wave-slot cap)
    if (grid > NT) grid = NT;
    dist_kernel<<<grid, 512, 0, stream>>>(x, y, centers, loss, counts, NT);

    finalize_kernel<<<1, 64, 0, stream>>>(loss, counts, out, N);
}

// Round 3
// 156.962 us; speedup vs baseline: 2.2659x; 1.0219x over previous
//
#include <hip/hip_runtime.h>

#define ALPHA 0.1f
#define NUM_CLASSES 10

typedef __attribute__((ext_vector_type(8))) short bf16x8;
typedef __attribute__((ext_vector_type(4))) float f32x4;

// ---------------------------------------------------------------------------
// ws layout (bytes):
//   loss  @ 0   : float[1]
//   counts@ 4   : uint[100]
// (zeroed each launch via hipMemsetAsync)
//
// ROUND 13: R12 minus the LDS-atomic combine (that was the 91us regression:
// 3072 same-address ds_add/ds_min per tile, 8-way contended).  Combine is
// back to R10's proven conflict-free pattern, widened to 128 points:
// per-wave partials in comb[8][128] (plain stores, 16-lane contiguous) +
// an 8-way tree on waves 0-1.  Kept from R12: 128-pt tiles, all 8 waves
// stage their own subtile (no idle waves), 2 barriers per 128 pts, counts
// via LDS + one 100-word flush per block (R10's 262k global atomics on 100
// hot words are gone).  MFMA math / u bits identical to R10.
// ---------------------------------------------------------------------------

__device__ __forceinline__ unsigned pack2(float a, float b) {
    // bf16(a) lo16 | bf16(b) hi16 (truncation -> exact Dekker hi split)
    return (__float_as_uint(b) & 0xFFFF0000u) | (__float_as_uint(a) >> 16);
}
__device__ __forceinline__ float truncbf(float a) {
    return __uint_as_float(__float_as_uint(a) & 0xFFFF0000u);
}

// 512 threads = 8 waves. Wave w owns centers [w*32, w*32+32) (M dim) and
// stages points [t*128 + w*16, +16) (N dim).  Lane: r = l&15 (point row),
// q = l>>4 (k-group of 8 floats).
__global__ __launch_bounds__(512, 4) void dist_kernel(
    const float* __restrict__ x,
    const int*   __restrict__ y,
    const float* __restrict__ centers,
    float* __restrict__ loss_acc,
    unsigned int* __restrict__ counts,
    int NT)
{
    // bstage[pt][f][lane] : 16 B per lane, contiguous-lane layout (b128)
    __shared__ __align__(16) char bstage[8 * 4 * 64 * 16];   // 32 KB
    __shared__ float x2s[128];
    __shared__ float c2s[256];
    __shared__ float    comb_swe[8][128];    // 4 KB
    __shared__ float    comb_swd[8][128];    // 4 KB
    __shared__ unsigned comb_best[8][128];   // 4 KB
    __shared__ unsigned counts_l[100];

    const int tid  = threadIdx.x;
    const int w    = tid >> 6;     // wave id = center group (32 centers)
    const int lane = tid & 63;
    const int q    = lane >> 4;    // k-group
    const int r    = lane & 15;    // point row within subtile

    if (tid < 100) counts_l[tid] = 0u;

    // ---- startup: center norms (one center per thread) ----
    if (tid < 256) {
        const float4* crow = (const float4*)(centers + tid * 64);
        float s = 0.f;
#pragma unroll
        for (int j = 0; j < 16; ++j) {
            float4 v = crow[j];
            s = fmaf(v.x, v.x, s); s = fmaf(v.y, v.y, s);
            s = fmaf(v.z, v.z, s); s = fmaf(v.w, v.w, s);
        }
        c2s[tid] = s;
    }

    // ---- startup: this wave's center A-frags, PRE-SCALED by -2 ----
    // af[ct][f]; f: 0=mh k0-31, 1=mh k32-63, 2=ml k0-31, 3=ml k32-63
    bf16x8 af[2][4];
#pragma unroll
    for (int ct = 0; ct < 2; ++ct) {
        const int row = w * 32 + ct * 16 + r;
        const float4* C = (const float4*)(centers + (size_t)row * 64);
        float4 v0 = C[q * 2], v1 = C[q * 2 + 1];       // k = q*8 .. q*8+7
        float4 v2 = C[8 + q * 2], v3 = C[9 + q * 2];   // k = 32+q*8 ..
        float4 m0 = make_float4(-2.f * v0.x, -2.f * v0.y, -2.f * v0.z, -2.f * v0.w);
        float4 m1 = make_float4(-2.f * v1.x, -2.f * v1.y, -2.f * v1.z, -2.f * v1.w);
        float4 m2 = make_float4(-2.f * v2.x, -2.f * v2.y, -2.f * v2.z, -2.f * v2.w);
        float4 m3 = make_float4(-2.f * v3.x, -2.f * v3.y, -2.f * v3.z, -2.f * v3.w);
        union { bf16x8 v; unsigned u[4]; } h0, h1, l0, l1;
        h0.u[0] = pack2(m0.x, m0.y); h0.u[1] = pack2(m0.z, m0.w);
        h0.u[2] = pack2(m1.x, m1.y); h0.u[3] = pack2(m1.z, m1.w);
        h1.u[0] = pack2(m2.x, m2.y); h1.u[1] = pack2(m2.z, m2.w);
        h1.u[2] = pack2(m3.x, m3.y); h1.u[3] = pack2(m3.z, m3.w);
        l0.u[0] = pack2(m0.x - truncbf(m0.x), m0.y - truncbf(m0.y));
        l0.u[1] = pack2(m0.z - truncbf(m0.z), m0.w - truncbf(m0.w));
        l0.u[2] = pack2(m1.x - truncbf(m1.x), m1.y - truncbf(m1.y));
        l0.u[3] = pack2(m1.z - truncbf(m1.z), m1.w - truncbf(m1.w));
        l1.u[0] = pack2(m2.x - truncbf(m2.x), m2.y - truncbf(m2.y));
        l1.u[1] = pack2(m2.z - truncbf(m2.z), m2.w - truncbf(m2.w));
        l1.u[2] = pack2(m3.x - truncbf(m3.x), m3.y - truncbf(m3.y));
        l1.u[3] = pack2(m3.z - truncbf(m3.z), m3.w - truncbf(m3.w));
        af[ct][0] = h0.v; af[ct][1] = h1.v; af[ct][2] = l0.v; af[ct][3] = l1.v;
    }

    // ---- prefetch first tile's x (every wave stages its own subtile) ----
    float4 pv0, pv1, pv2, pv3;
    {
        const int row = blockIdx.x * 128 + w * 16 + r;
        const float4* X = (const float4*)(x + (size_t)row * 64);
        pv0 = X[q * 2]; pv1 = X[q * 2 + 1];
        pv2 = X[8 + q * 2]; pv3 = X[9 + q * 2];
    }

    __syncthreads();   // startup: c2s visible

    // this lane's 8 center norms + 1: u = (x2 + c2 + 1) + (-2 x.c)
    float c2r1[2][4];
#pragma unroll
    for (int ct = 0; ct < 2; ++ct) {
        float4 v = *(const float4*)(c2s + w * 32 + ct * 16 + q * 4);
        c2r1[ct][0] = v.x + 1.f; c2r1[ct][1] = v.y + 1.f;
        c2r1[ct][2] = v.z + 1.f; c2r1[ct][3] = v.w + 1.f;
    }

    float loss_local = 0.f;

    for (int t = blockIdx.x; t < NT; t += gridDim.x) {
        // ---- y prefetch for this tile's combine (latency spans the tile) ----
        int ylab = 0;
        if (tid < 128) ylab = y[t * 128 + tid];

        // ---- stage: every wave converts its subtile from prefetched regs ----
        {
            float4 v0 = pv0, v1 = pv1, v2 = pv2, v3 = pv3;

            // issue next tile's loads immediately (latency hidden by MFMA phase)
            const int tn = t + gridDim.x;
            if (tn < NT) {
                const int row = tn * 128 + w * 16 + r;
                const float4* X = (const float4*)(x + (size_t)row * 64);
                pv0 = X[q * 2]; pv1 = X[q * 2 + 1];
                pv2 = X[8 + q * 2]; pv3 = X[9 + q * 2];
            }

            float p = v0.x * v0.x;
            p = fmaf(v0.y, v0.y, p); p = fmaf(v0.z, v0.z, p); p = fmaf(v0.w, v0.w, p);
            p = fmaf(v1.x, v1.x, p); p = fmaf(v1.y, v1.y, p); p = fmaf(v1.z, v1.z, p); p = fmaf(v1.w, v1.w, p);
            p = fmaf(v2.x, v2.x, p); p = fmaf(v2.y, v2.y, p); p = fmaf(v2.z, v2.z, p); p = fmaf(v2.w, v2.w, p);
            p = fmaf(v3.x, v3.x, p); p = fmaf(v3.y, v3.y, p); p = fmaf(v3.z, v3.z, p); p = fmaf(v3.w, v3.w, p);
            p += __shfl_xor(p, 16);
            p += __shfl_xor(p, 32);
            if (q == 0) x2s[w * 16 + r] = p;

            union { bf16x8 v; uint4 u4; unsigned u[4]; } h0, h1, l0, l1;
            h0.u[0] = pack2(v0.x, v0.y); h0.u[1] = pack2(v0.z, v0.w);
            h0.u[2] = pack2(v1.x, v1.y); h0.u[3] = pack2(v1.z, v1.w);
            h1.u[0] = pack2(v2.x, v2.y); h1.u[1] = pack2(v2.z, v2.w);
            h1.u[2] = pack2(v3.x, v3.y); h1.u[3] = pack2(v3.z, v3.w);
            l0.u[0] = pack2(v0.x - truncbf(v0.x), v0.y - truncbf(v0.y));
            l0.u[1] = pack2(v0.z - truncbf(v0.z), v0.w - truncbf(v0.w));
            l0.u[2] = pack2(v1.x - truncbf(v1.x), v1.y - truncbf(v1.y));
            l0.u[3] = pack2(v1.z - truncbf(v1.z), v1.w - truncbf(v1.w));
            l1.u[0] = pack2(v2.x - truncbf(v2.x), v2.y - truncbf(v2.y));
            l1.u[1] = pack2(v2.z - truncbf(v2.z), v2.w - truncbf(v2.w));
            l1.u[2] = pack2(v3.x - truncbf(v3.x), v3.y - truncbf(v3.y));
            l1.u[3] = pack2(v3.z - truncbf(v3.z), v3.w - truncbf(v3.w));
            *(uint4*)(bstage + (((w * 4 + 0) * 64 + lane) << 4)) = h0.u4;
            *(uint4*)(bstage + (((w * 4 + 1) * 64 + lane) << 4)) = h1.u4;
            *(uint4*)(bstage + (((w * 4 + 2) * 64 + lane) << 4)) = l0.u4;
            *(uint4*)(bstage + (((w * 4 + 3) * 64 + lane) << 4)) = l1.u4;
        }
        __syncthreads();   // barA: frags + x2s visible; prev combine done

        // ---- per 16-point subtile: MFMA (acc preloaded) then epilogue ----
#pragma unroll
        for (int pt = 0; pt < 8; ++pt) {
            union { uint4 u4; bf16x8 v; } b0, b1, b2, b3;
            b0.u4 = *(const uint4*)(bstage + (((pt * 4 + 0) * 64 + lane) << 4));
            b1.u4 = *(const uint4*)(bstage + (((pt * 4 + 1) * 64 + lane) << 4));
            b2.u4 = *(const uint4*)(bstage + (((pt * 4 + 2) * 64 + lane) << 4));
            b3.u4 = *(const uint4*)(bstage + (((pt * 4 + 3) * 64 + lane) << 4));
            const float x2p = x2s[pt * 16 + r];

            f32x4 acc[2];
#pragma unroll
            for (int ct = 0; ct < 2; ++ct) {
                f32x4 a;
                a[0] = x2p + c2r1[ct][0]; a[1] = x2p + c2r1[ct][1];
                a[2] = x2p + c2r1[ct][2]; a[3] = x2p + c2r1[ct][3];
                a = __builtin_amdgcn_mfma_f32_16x16x32_bf16(af[ct][0], b0.v, a, 0, 0, 0); // mh.xh
                a = __builtin_amdgcn_mfma_f32_16x16x32_bf16(af[ct][1], b1.v, a, 0, 0, 0);
                a = __builtin_amdgcn_mfma_f32_16x16x32_bf16(af[ct][2], b0.v, a, 0, 0, 0); // ml.xh
                a = __builtin_amdgcn_mfma_f32_16x16x32_bf16(af[ct][3], b1.v, a, 0, 0, 0);
                a = __builtin_amdgcn_mfma_f32_16x16x32_bf16(af[ct][0], b2.v, a, 0, 0, 0); // mh.xl
                a = __builtin_amdgcn_mfma_f32_16x16x32_bf16(af[ct][1], b3.v, a, 0, 0, 0);
                acc[ct] = a;
            }

            float swe = 0.f, swdu = 0.f;
            unsigned best = 0xFFFFFFFFu;
#pragma unroll
            for (int ct = 0; ct < 2; ++ct) {
#pragma unroll
                for (int reg = 0; reg < 4; ++reg) {
                    const float u = acc[ct][reg];          // u = 1 + d
                    const unsigned kid = (unsigned)(w * 32 + ct * 16 + q * 4 + reg);
                    best = min(best, (__float_as_uint(u) & 0xFFFFFF00u) | kid);
                    float wg = exp2f(-ALPHA * __log2f(u));
                    swe += wg;
                    swdu = fmaf(wg, u, swdu);
                }
            }
            // reduce over q (4 lanes share point pt*16+r)
            swe += __shfl_xor(swe, 16); swe += __shfl_xor(swe, 32);
            swdu += __shfl_xor(swdu, 16); swdu += __shfl_xor(swdu, 32);
            best = min(best, (unsigned)__shfl_xor((int)best, 16));
            best = min(best, (unsigned)__shfl_xor((int)best, 32));
            if (q == 0) {
                comb_swe[w][pt * 16 + r]  = swe;
                comb_swd[w][pt * 16 + r]  = swdu;
                comb_best[w][pt * 16 + r] = best;
            }
        }
        __syncthreads();   // barB: all groups' partials visible

        // ---- combine across 8 center groups (waves 0-1, one point each) ----
        if (tid < 128) {
            float SWE = comb_swe[0][tid], SWD = comb_swd[0][tid];
            unsigned BEST = comb_best[0][tid];
#pragma unroll
            for (int g = 1; g < 8; ++g) {
                SWE += comb_swe[g][tid];
                SWD += comb_swd[g][tid];
                BEST = min(BEST, comb_best[g][tid]);
            }
            loss_local += SWD / SWE - 1.f;   // Sum w*d / Sum w  ==  swdu/swe - 1
            const unsigned bk = BEST & 0xFFu;
            if (bk < NUM_CLASSES) {
                atomicAdd(&counts_l[bk * NUM_CLASSES + ylab], 1u);
            }
        }
        // next iteration's barA protects bstage / x2s / comb_* reuse
    }

    // per-wave loss reduce -> one global atomic per contributing wave
    if (w < 2) {
        float v = loss_local;
#pragma unroll
        for (int o = 32; o > 0; o >>= 1) v += __shfl_down(v, o);
        if (lane == 0) atomicAdd(loss_acc, v);
    }

    __syncthreads();
    if (tid < 100) {
        const unsigned c = counts_l[tid];
        if (c) atomicAdd(&counts[tid], c);
    }
}

// ---------------------------------------------------------------------------
// Finalize: greedy cluster->label assignment, exactly mirroring the reference.
// ---------------------------------------------------------------------------

__global__ void finalize_kernel(
    const float* __restrict__ loss_acc,
    const unsigned int* __restrict__ counts,
    float* __restrict__ out,
    int N)
{
    if (threadIdx.x == 0 && blockIdx.x == 0) {
        float c[NUM_CLASSES][NUM_CLASSES];
        for (int i = 0; i < NUM_CLASSES; ++i)
            for (int j = 0; j < NUM_CLASSES; ++j)
                c[i][j] = (float)counts[i * NUM_CLASSES + j];

        bool used[NUM_CLASSES];
        for (int i = 0; i < NUM_CLASSES; ++i) used[i] = false;

        float correct = 0.f;
        for (int i = 0; i < NUM_CLASSES; ++i) {
            float rowsum = 0.f;
            for (int j = 0; j < NUM_CLASSES; ++j) rowsum += c[i][j];
            bool has_points = rowsum > 0.f;

            int label = 0;
            float mx = c[i][0];
            for (int j = 1; j < NUM_CLASSES; ++j)
                if (c[i][j] > mx) { mx = c[i][j]; label = j; }

            if (used[label]) {
                float mm = used[0] ? 0.f : c[i][0];
                int l2 = 0;
                for (int j = 1; j < NUM_CLASSES; ++j) {
                    float v = used[j] ? 0.f : c[i][j];
                    if (v > mm) { mm = v; l2 = j; }
                }
                label = l2;
            }

            if (has_points) {
                correct += c[i][label];
                used[label] = true;
            }
        }
        out[0] = loss_acc[0];
        out[1] = correct / (float)N;
    }
}

// ---------------------------------------------------------------------------

extern "C" void kernel_launch(void* const* d_in, const int* in_sizes, int n_in,
                              void* d_out, int out_size, void* d_ws, size_t ws_size,
                              hipStream_t stream)
{
    const float* x       = (const float*)d_in[0];
    const int*   y       = (const int*)d_in[1];
    const float* centers = (const float*)d_in[2];
    float* out = (float*)d_out;

    const int N  = in_sizes[0] / 64;  // D = 64
    const int NT = N / 128;           // 128-point tiles

    float* loss          = (float*)d_ws;                       // 4 B
    unsigned int* counts = (unsigned int*)((char*)d_ws + 4);   // 400 B

    hipMemsetAsync(d_ws, 0, 512, stream);

    int grid = 1024;
    if (grid > NT) grid = NT;
    dist_kernel<<<grid, 512, 0, stream>>>(x, y, centers, loss, counts, NT);

    finalize_kernel<<<1, 64, 0, stream>>>(loss, counts, out, N);
}